// Round 3
// baseline (530.747 us; speedup 1.0000x reference)
//
#include <hip/hip_runtime.h>

typedef __bf16 bf16;
typedef __attribute__((ext_vector_type(4))) bf16 bf16x4;
typedef __attribute__((ext_vector_type(8))) bf16 bf16x8;
typedef __attribute__((ext_vector_type(4))) float f32x4;
typedef __attribute__((ext_vector_type(4))) int i32x4;

#define MFMA_BF16(a, b, c) __builtin_amdgcn_mfma_f32_16x16x32_bf16((a), (b), (c), 0, 0, 0)

constexpr int S_LEN = 2048;
constexpr int EMB   = 1024;
constexpr int NHEAD = 16;
constexpr int HDIM  = 64;
constexpr int BATCH = 4;
constexpr int NTOK  = BATCH * S_LEN;        // 8192
constexpr int ME4   = NTOK * EMB / 4;       // 2097152
constexpr int WE4   = EMB * EMB / 4;        // 262144 = 2^18
constexpr int MASK4 = NTOK / 4;             // 2048
constexpr float QSCALE = 0.125f * 1.44269504088896340736f;  // 1/sqrt(64) * log2(e)

// async global->LDS, 16B per lane (m97 pattern: LDS dest = uniform base + lane*16)
__device__ __forceinline__ void gload_lds16(const bf16* g, bf16* l) {
    __builtin_amdgcn_global_load_lds(
        (const __attribute__((address_space(1))) void*)g,
        (__attribute__((address_space(3))) void*)l, 16, 0, 0);
}

__device__ __forceinline__ f32x4 vmax4(f32x4 a, f32x4 b) {
    f32x4 r;
    r[0] = fmaxf(a[0], b[0]); r[1] = fmaxf(a[1], b[1]);
    r[2] = fmaxf(a[2], b[2]); r[3] = fmaxf(a[3], b[3]);
    return r;
}

// ---------------------------------------------------------------------------
// One-shot prep: fp32->bf16 for x and the 4 weight matrices, plus mask ->
// f32 additive-bias table (0 / -3e38). Exactly ME4+4*WE4+MASK4 units.
// ---------------------------------------------------------------------------
__global__ __launch_bounds__(256)
void prep_kern(const float* __restrict__ x,  const float* __restrict__ wq,
               const float* __restrict__ wk, const float* __restrict__ wv,
               const float* __restrict__ wo, const int* __restrict__ mask,
               bf16* __restrict__ xb, bf16* __restrict__ wqb, bf16* __restrict__ wkb,
               bf16* __restrict__ wvb, bf16* __restrict__ wob, float* __restrict__ biasg)
{
    int i = blockIdx.x * 256 + threadIdx.x;
    if (i < ME4 + 4 * WE4) {
        const float* src; bf16* dst; int off;
        if (i < ME4) { src = x; dst = xb; off = i; }
        else {
            int j = i - ME4, seg = j >> 18;
            off = j & (WE4 - 1);
            src = seg == 0 ? wq : (seg == 1 ? wk : (seg == 2 ? wv : wo));
            dst = seg == 0 ? wqb : (seg == 1 ? wkb : (seg == 2 ? wvb : wob));
        }
        f32x4 v = ((const f32x4*)src)[off];
        bf16x4 o;
        o[0] = (bf16)v[0]; o[1] = (bf16)v[1]; o[2] = (bf16)v[2]; o[3] = (bf16)v[3];
        ((bf16x4*)dst)[off] = o;
    } else {
        int m = i - (ME4 + 4 * WE4);
        i32x4 mv = ((const i32x4*)mask)[m];
        f32x4 f;
        #pragma unroll
        for (int r = 0; r < 4; ++r) f[r] = mv[r] ? 0.f : -3.0e38f;
        ((f32x4*)biasg)[m] = f;
    }
}

// ---------------------------------------------------------------------------
// NT GEMM, m97 structure: C[M,N] = (A[M,K]*W[N,K]^T + bias)*cs. 128x128 tile,
// BK=32, 4 waves 2x2. fused=1: grid (64,24), seg=y>>3 picks {Q,K,V}; Q output
// pre-scaled by QSCALE; V scattered to Vt[b,h,d,s] (packed 8B). fused=0: fp32 C.
// ---------------------------------------------------------------------------
__global__ __launch_bounds__(256)
void gemm_bt(const bf16* __restrict__ A,
             const bf16* __restrict__ W0, const bf16* __restrict__ W1, const bf16* __restrict__ W2,
             const float* __restrict__ b0, const float* __restrict__ b1, const float* __restrict__ b2,
             void* __restrict__ d0, void* __restrict__ d1, void* __restrict__ d2,
             int fused)
{
    __shared__ bf16 al[128 * 32];
    __shared__ bf16 bl[128 * 32];

    int seg, mode, n0;
    if (fused) { seg = blockIdx.y >> 3; n0 = (blockIdx.y & 7) * 128; mode = (seg == 2) ? 1 : 0; }
    else       { seg = 0;              n0 = blockIdx.y * 128;        mode = 2; }
    const bf16*  W    = seg == 0 ? W0 : (seg == 1 ? W1 : W2);
    const float* bias = seg == 0 ? b0 : (seg == 1 ? b1 : b2);
    void*        C    = seg == 0 ? d0 : (seg == 1 ? d1 : d2);
    const float  cs   = (fused && seg == 0) ? QSCALE : 1.0f;

    const int tid  = threadIdx.x;
    const int lane = tid & 63;
    const int w    = tid >> 6;
    const int quad = lane >> 4;
    const int l16  = lane & 15;
    const int wm   = (w >> 1) * 64;
    const int wn   = (w & 1) * 64;
    const int m0   = blockIdx.x * 128;

    f32x4 acc[4][4] = {};

    for (int k0 = 0; k0 < EMB; k0 += 32) {
        #pragma unroll
        for (int c = 0; c < 2; ++c) {
            int idx = c * 256 + tid;
            int row = idx >> 2, kc = idx & 3;
            gload_lds16(A + (size_t)(m0 + row) * EMB + k0 + kc * 8, &al[idx * 8]);
            gload_lds16(W + (size_t)(n0 + row) * EMB + k0 + kc * 8, &bl[idx * 8]);
        }
        __syncthreads();

        bf16x8 afrag[4], bfrag[4];
        #pragma unroll
        for (int t = 0; t < 4; ++t)
            afrag[t] = *(const bf16x8*)&al[(wm + t * 16 + l16) * 32 + quad * 8];
        #pragma unroll
        for (int t = 0; t < 4; ++t)
            bfrag[t] = *(const bf16x8*)&bl[(wn + t * 16 + l16) * 32 + quad * 8];

        #pragma unroll
        for (int mt = 0; mt < 4; ++mt)
            #pragma unroll
            for (int nt = 0; nt < 4; ++nt)
                acc[mt][nt] = MFMA_BF16(afrag[mt], bfrag[nt], acc[mt][nt]);

        __syncthreads();
    }

    // epilogue: C-layout row = quad*4+r, col = l16 (m89-verified)
    #pragma unroll
    for (int mt = 0; mt < 4; ++mt) {
        #pragma unroll
        for (int nt = 0; nt < 4; ++nt) {
            int col = n0 + wn + nt * 16 + l16;
            float bvs = bias[col] * cs;
            int row0 = m0 + wm + mt * 16 + quad * 4;
            if (mode == 1) {
                int bb = row0 >> 11, s0 = row0 & 2047;
                int hh = col >> 6,   d  = col & 63;
                bf16x4 pk;
                #pragma unroll
                for (int r = 0; r < 4; ++r) pk[r] = (bf16)(acc[mt][nt][r] + bvs);
                *(bf16x4*)((bf16*)C + (size_t)((bb * NHEAD + hh) * HDIM + d) * S_LEN + s0) = pk;
            } else if (mode == 0) {
                #pragma unroll
                for (int r = 0; r < 4; ++r)
                    ((bf16*)C)[(size_t)(row0 + r) * EMB + col] = (bf16)(acc[mt][nt][r] * cs + bvs);
            } else {
                #pragma unroll
                for (int r = 0; r < 4; ++r)
                    ((float*)C)[(size_t)(row0 + r) * EMB + col] = acc[mt][nt][r] + bvs;
            }
        }
    }
}

// ---------------------------------------------------------------------------
// Flash attention, S^T orientation (query on l16, keys on regs). Q pre-scaled,
// mask bias from global f32 table. No block barriers; all LDS wave-private.
// LDS = 34816 B exactly -> 4 blocks/CU; launch_bounds(256,4) pins VGPR<=128.
// Grid (S/128, H, B) = 1024 blocks = 4/CU, one clean residency round.
// ---------------------------------------------------------------------------
__global__ __launch_bounds__(256, 4)
void flash_attn(const bf16* __restrict__ qg, const bf16* __restrict__ kg,
                const bf16* __restrict__ vtg, const float* __restrict__ biasg,
                bf16* __restrict__ ctx)
{
    __shared__ bf16 plds[128 * 136];   // 272B rows, 16B-aligned

    const int tid  = threadIdx.x;
    const int lane = tid & 63;
    const int w    = tid >> 6;
    const int quad = lane >> 4;
    const int l16  = lane & 15;
    const int b    = blockIdx.z;
    const int h    = blockIdx.y;
    const int q0   = blockIdx.x * 128;

    // Q fragments (B-operand: n=query=l16, k=quad*8+j), resident all kernel
    bf16x8 qf[2][2];
    #pragma unroll
    for (int mt = 0; mt < 2; ++mt)
        #pragma unroll
        for (int ks = 0; ks < 2; ++ks) {
            int row = b * S_LEN + q0 + w * 32 + mt * 16 + l16;
            qf[mt][ks] = *(const bf16x8*)(qg + (size_t)row * EMB + h * HDIM + ks * 32 + quad * 8);
        }

    float mrow[2] = {-1e30f, -1e30f}, lrow[2] = {0.f, 0.f};
    f32x4 oacc[2][4] = {};

    for (int kt = 0; kt < 16; ++kt) {
        const int k0 = kt * 128;

        // ---- S^T = K Q^T: C[key=quad*4+r][query=l16] per (nt,mt) ----
        f32x4 sacc[8][2] = {};
        #pragma unroll
        for (int nt = 0; nt < 8; ++nt) {
            int krow = b * S_LEN + k0 + nt * 16 + l16;
            #pragma unroll
            for (int ks = 0; ks < 2; ++ks) {
                bf16x8 kf = *(const bf16x8*)(kg + (size_t)krow * EMB + h * HDIM + ks * 32 + quad * 8);
                sacc[nt][0] = MFMA_BF16(kf, qf[0][ks], sacc[nt][0]);
                sacc[nt][1] = MFMA_BF16(kf, qf[1][ks], sacc[nt][1]);
            }
        }

        // ---- + mask bias, max over keys (vectorized f32x4 + 2 shuffles) ----
        f32x4 rmax4[2];
        #pragma unroll
        for (int mt = 0; mt < 2; ++mt)
            #pragma unroll
            for (int r = 0; r < 4; ++r) rmax4[mt][r] = -3.0e38f;
        #pragma unroll
        for (int nt = 0; nt < 8; ++nt) {
            f32x4 b4 = *(const f32x4*)(biasg + b * S_LEN + k0 + nt * 16 + quad * 4);
            #pragma unroll
            for (int mt = 0; mt < 2; ++mt) {
                sacc[nt][mt] = sacc[nt][mt] + b4;
                rmax4[mt] = vmax4(rmax4[mt], sacc[nt][mt]);
            }
        }
        float rmax[2], mnew[2], alpha[2];
        #pragma unroll
        for (int mt = 0; mt < 2; ++mt) {
            rmax[mt] = fmaxf(fmaxf(rmax4[mt][0], rmax4[mt][1]),
                             fmaxf(rmax4[mt][2], rmax4[mt][3]));
            rmax[mt] = fmaxf(rmax[mt], __shfl_xor(rmax[mt], 16));
            rmax[mt] = fmaxf(rmax[mt], __shfl_xor(rmax[mt], 32));
            mnew[mt]  = fmaxf(mrow[mt], rmax[mt]);
            alpha[mt] = __builtin_amdgcn_exp2f(mrow[mt] - mnew[mt]);
            mrow[mt]  = mnew[mt];
        }

        // ---- exp2, packed P writes (b64), vector sums ----
        f32x4 rsum4[2] = {};
        #pragma unroll
        for (int nt = 0; nt < 8; ++nt)
            #pragma unroll
            for (int mt = 0; mt < 2; ++mt) {
                f32x4 p4;
                #pragma unroll
                for (int r = 0; r < 4; ++r)
                    p4[r] = __builtin_amdgcn_exp2f(sacc[nt][mt][r] - mnew[mt]);
                rsum4[mt] = rsum4[mt] + p4;
                bf16x4 pk;
                #pragma unroll
                for (int r = 0; r < 4; ++r) pk[r] = (bf16)p4[r];
                *(bf16x4*)&plds[(w * 32 + mt * 16 + l16) * 136 + nt * 16 + quad * 4] = pk;
            }
        #pragma unroll
        for (int mt = 0; mt < 2; ++mt) {
            float rs = (rsum4[mt][0] + rsum4[mt][1]) + (rsum4[mt][2] + rsum4[mt][3]);
            rs += __shfl_xor(rs, 16);
            rs += __shfl_xor(rs, 32);
            lrow[mt] = lrow[mt] * alpha[mt] + rs;
        }

        // ---- alpha broadcast l16-layout -> (quad,r)-layout via shfl ----
        #pragma unroll
        for (int mt = 0; mt < 2; ++mt) {
            f32x4 a4;
            #pragma unroll
            for (int r = 0; r < 4; ++r) a4[r] = __shfl(alpha[mt], quad * 4 + r);
            #pragma unroll
            for (int dt = 0; dt < 4; ++dt)
                #pragma unroll
                for (int r = 0; r < 4; ++r)
                    oacc[mt][dt][r] *= a4[r];
        }

        // ---- O += P V (P A-operand from LDS b128, Vt NT B-operand) ----
        #pragma unroll
        for (int ks = 0; ks < 4; ++ks) {
            bf16x8 pf0 = *(const bf16x8*)&plds[(w * 32 + l16) * 136 + ks * 32 + quad * 8];
            bf16x8 pf1 = *(const bf16x8*)&plds[(w * 32 + 16 + l16) * 136 + ks * 32 + quad * 8];
            #pragma unroll
            for (int dt = 0; dt < 4; ++dt) {
                bf16x8 vf = *(const bf16x8*)(vtg + (size_t)((b * NHEAD + h) * HDIM + dt * 16 + l16) * S_LEN
                                             + k0 + ks * 32 + quad * 8);
                oacc[0][dt] = MFMA_BF16(pf0, vf, oacc[0][dt]);
                oacc[1][dt] = MFMA_BF16(pf1, vf, oacc[1][dt]);
            }
        }
    }

    // ---- epilogue: 1/l broadcast via shfl, store ctx[b,s,h,d] ----
    float invl[2];
    #pragma unroll
    for (int mt = 0; mt < 2; ++mt) invl[mt] = lrow[mt] > 0.f ? 1.f / lrow[mt] : 0.f;
    #pragma unroll
    for (int mt = 0; mt < 2; ++mt) {
        f32x4 inv4;
        #pragma unroll
        for (int r = 0; r < 4; ++r) inv4[r] = __shfl(invl[mt], quad * 4 + r);
        #pragma unroll
        for (int r = 0; r < 4; ++r) {
            size_t row = (size_t)(b * S_LEN + q0 + w * 32 + mt * 16 + quad * 4 + r);
            #pragma unroll
            for (int dt = 0; dt < 4; ++dt)
                ctx[row * EMB + h * HDIM + dt * 16 + l16] = (bf16)(oacc[mt][dt][r] * inv4[r]);
        }
    }
}

extern "C" void kernel_launch(void* const* d_in, const int* in_sizes, int n_in,
                              void* d_out, int out_size, void* d_ws, size_t ws_size,
                              hipStream_t stream)
{
    const float* x   = (const float*)d_in[0];
    const int*  mask = (const int*)d_in[1];
    const float* Wq  = (const float*)d_in[2];
    const float* bq  = (const float*)d_in[3];
    const float* Wk  = (const float*)d_in[4];
    const float* bk  = (const float*)d_in[5];
    const float* Wv  = (const float*)d_in[6];
    const float* bv  = (const float*)d_in[7];
    const float* Wo  = (const float*)d_in[8];
    const float* bo  = (const float*)d_in[9];
    (void)in_sizes; (void)n_in; (void)out_size; (void)ws_size;

    const size_t me = (size_t)NTOK * EMB;
    const size_t we = (size_t)EMB * EMB;
    bf16* xb    = (bf16*)d_ws;
    bf16* qb    = xb  + me;
    bf16* kb    = qb  + me;
    bf16* vt    = kb  + me;       // V transposed [b,h,d,s]
    bf16* wqb   = vt  + me;
    bf16* wkb   = wqb + we;
    bf16* wvb   = wkb + we;
    bf16* wob   = wvb + we;
    float* biasg = (float*)(wob + we);
    bf16* cx    = xb;             // alias: xb consumed by qkv gemm before flash writes cx

    prep_kern<<<(ME4 + 4 * WE4 + MASK4) / 256, 256, 0, stream>>>(
        x, Wq, Wk, Wv, Wo, mask, xb, wqb, wkb, wvb, wob, biasg);

    gemm_bt<<<dim3(NTOK / 128, 24), 256, 0, stream>>>(
        xb, wqb, wkb, wvb, bq, bk, bv, qb, kb, vt, 1);

    flash_attn<<<dim3(S_LEN / 128, NHEAD, BATCH), 256, 0, stream>>>(qb, kb, vt, biasg, cx);

    gemm_bt<<<dim3(NTOK / 128, EMB / 128), 256, 0, stream>>>(
        cx, wob, wob, wob, bo, bo, bo, d_out, d_out, d_out, 0);
}